// Round 6
// baseline (158.419 us; speedup 1.0000x reference)
//
#include <hip/hip_runtime.h>
#include <hip/hip_fp16.h>
#include <math.h>

#define B_ 4
#define N_ 32768
#define M_ 8192
#define K_ 16
#define D_ 64
#define O_ 64

typedef __attribute__((ext_vector_type(8))) short bf16x8;
typedef __attribute__((ext_vector_type(4))) float f32x4;

// float -> bf16 bits, round-to-nearest-even (inputs are finite normals)
static __device__ __forceinline__ short f2bf(float f) {
    unsigned u = __float_as_uint(f);
    u += 0x7fffu + ((u >> 16) & 1u);
    return (short)(u >> 16);
}

// ---------------------------------------------------------------------------
// Kernel A (MFMA, no LDS). PROBE: internal repeat loop (reps, rep_off=0 from
// host, opaque to compiler) so the dispatch exceeds the 44us harness fills
// and shows up in top-5 with counters. Work per rep identical & deterministic.
// ---------------------------------------------------------------------------
__global__ __launch_bounds__(256)
void gemm_gc(const float* __restrict__ x, const float* __restrict__ xs,
             const float* __restrict__ W, const float* __restrict__ bias,
             __half* __restrict__ G, __half* __restrict__ C,
             int reps, long rep_off) {
    const int tid = threadIdx.x;
    const int l   = tid & 63;
    const int lr  = l & 15;          // A-row / B-col within tile
    const int kg  = l >> 4;          // k-group (8 consecutive k each)
    const int job = blockIdx.x * 4 + (tid >> 6);     // 0..5119, 32 rows each
    const bool cmode = job >= (B_ * N_) / 32;        // jobs 4096..5119

    // ---- B fragments: bf[s][t] covers k = s*32 + kg*8 + 0..7, o = t*16 + lr
    bf16x8 bf[2][4];
    float  binit[4] = {0.f, 0.f, 0.f, 0.f};
    #pragma unroll
    for (int t = 0; t < 4; ++t) {
        #pragma unroll
        for (int s = 0; s < 2; ++s) {
            const float* wp = W + (size_t)(t * 16 + lr) * 128 + s * 32 + kg * 8;
            float4 f0 = *(const float4*)wp;
            float4 f1 = *(const float4*)(wp + 4);
            if (cmode) {
                float4 g0 = *(const float4*)(wp + 64);
                float4 g1 = *(const float4*)(wp + 68);
                f0.x = g0.x - f0.x; f0.y = g0.y - f0.y;
                f0.z = g0.z - f0.z; f0.w = g0.w - f0.w;
                f1.x = g1.x - f1.x; f1.y = g1.y - f1.y;
                f1.z = g1.z - f1.z; f1.w = g1.w - f1.w;
            }
            bf16x8 v;
            v[0] = f2bf(f0.x); v[1] = f2bf(f0.y); v[2] = f2bf(f0.z); v[3] = f2bf(f0.w);
            v[4] = f2bf(f1.x); v[5] = f2bf(f1.y); v[6] = f2bf(f1.z); v[7] = f2bf(f1.w);
            bf[s][t] = v;
        }
    }
    if (cmode) {
        #pragma unroll
        for (int t = 0; t < 4; ++t) binit[t] = bias[t * 16 + lr];
    }

    const long rows0 = (cmode ? (long)(job - (B_ * N_) / 32) : (long)job) * 32;
    const float* src0 = cmode ? xs : x;
    __half* dst0 = cmode ? C : G;

    for (int rep = 0; rep < reps; ++rep) {
        const float* src = src0 + rep * rep_off;          // rep_off == 0
        __half* dst = dst0 + rep * rep_off;

        #pragma unroll
        for (int i = 0; i < 2; ++i) {
            const long r0 = rows0 + i * 16;

            bf16x8 af[2];
            #pragma unroll
            for (int s = 0; s < 2; ++s) {
                const float* xp = src + (size_t)(r0 + lr) * 64 + s * 32 + kg * 8;
                float4 f0 = *(const float4*)xp;
                float4 f1 = *(const float4*)(xp + 4);
                bf16x8 v;
                v[0] = f2bf(f0.x); v[1] = f2bf(f0.y); v[2] = f2bf(f0.z); v[3] = f2bf(f0.w);
                v[4] = f2bf(f1.x); v[5] = f2bf(f1.y); v[6] = f2bf(f1.z); v[7] = f2bf(f1.w);
                af[s] = v;
            }

            f32x4 acc[4];
            #pragma unroll
            for (int t = 0; t < 4; ++t) {
                f32x4 a = {binit[t], binit[t], binit[t], binit[t]};
                a = __builtin_amdgcn_mfma_f32_16x16x32_bf16(af[0], bf[0][t], a, 0, 0, 0);
                a = __builtin_amdgcn_mfma_f32_16x16x32_bf16(af[1], bf[1][t], a, 0, 0, 0);
                acc[t] = a;
            }

            // D: lane holds rows (kg*4 + r), col lr, for 4 o-tiles t.
            // Permuted row storage: element lr*4 + t -> 4 contiguous fp16.
            #pragma unroll
            for (int r = 0; r < 4; ++r) {
                unsigned lo = (unsigned)__half_as_ushort(__float2half(acc[0][r]))
                            | ((unsigned)__half_as_ushort(__float2half(acc[1][r])) << 16);
                unsigned hi = (unsigned)__half_as_ushort(__float2half(acc[2][r]))
                            | ((unsigned)__half_as_ushort(__float2half(acc[3][r])) << 16);
                __half* hp = dst + (size_t)(r0 + kg * 4 + r) * 64 + lr * 4;
                int2 pv; pv.x = (int)lo; pv.y = (int)hi;
                *(int2*)hp = pv;
            }
        }
    }
}

// ---------------------------------------------------------------------------
// Kernel B. PROBE: same internal repeat trick (reps, rep_off=0).
// Batch-affine XCD swizzle kept from R5 (neutral). Structure unchanged.
// ---------------------------------------------------------------------------
__global__ __launch_bounds__(512)
void gather_max(const int* __restrict__ idx, const __half* __restrict__ G,
                const __half* __restrict__ C, float* __restrict__ out,
                int reps, long rep_off) {
    __shared__ int   ldsI[512];        // 32 m x 16 k
    __shared__ float ldsT[64 * 33];
    const int tid = threadIdx.x;
    const int blk = blockIdx.x;          // 0..1023
    const int xcd  = blk & 7;
    const int slot = blk >> 3;           // 0..127
    const int bb   = xcd >> 1;           // batch on XCD pair {2c, 2c+1}
    const int m0   = ((((xcd & 1) << 7) + slot) << 5);

    ldsI[tid] = idx[((size_t)bb * M_ + m0) * 16 + tid];
    __syncthreads();

    const int j  = tid & 63;
    const int wv = tid >> 6;             // 0..7
    const int o_orig = (j & 3) * 16 + (j >> 2);

    for (int rep = 0; rep < reps; ++rep) {
        const __half* Gb = G + (size_t)bb * N_ * 64 + j + rep * rep_off;
        const __half* Cr = C + rep * rep_off;
        float* outr = out + rep * rep_off;

        #pragma unroll
        for (int mm = 0; mm < 4; ++mm) {
            const int mloc = wv * 4 + mm;
            int rr[16];
            #pragma unroll
            for (int k4 = 0; k4 < 4; ++k4) {
                int4 q = *(const int4*)&ldsI[mloc * 16 + k4 * 4];
                rr[k4 * 4 + 0] = q.x; rr[k4 * 4 + 1] = q.y;
                rr[k4 * 4 + 2] = q.z; rr[k4 * 4 + 3] = q.w;
            }
            float best = -INFINITY;
            #pragma unroll
            for (int k = 0; k < 16; ++k)
                best = fmaxf(best, __half2float(Gb[(size_t)rr[k] * 64]));
            float cv = __half2float(Cr[((size_t)bb * M_ + m0 + mloc) * 64 + j]);
            float r = best + cv;
            ldsT[o_orig * 33 + mloc] = r > 0.f ? r : 0.f;
        }
        __syncthreads();

        const int o  = tid >> 3;
        const int ms = (tid & 7) * 4;
        float4 v = make_float4(ldsT[o * 33 + ms + 0], ldsT[o * 33 + ms + 1],
                               ldsT[o * 33 + ms + 2], ldsT[o * 33 + ms + 3]);
        *(float4*)(outr + ((size_t)bb * 64 + o) * M_ + m0 + ms) = v;
        __syncthreads();   // protect ldsT before next rep rewrites it
    }
}

// ---------------------------------------------------------------------------
// Naive exact fallback (only if ws too small).
// ---------------------------------------------------------------------------
__global__ void naive_all(const float* __restrict__ x, const float* __restrict__ xs,
                          const int* __restrict__ idx, const float* __restrict__ W,
                          const float* __restrict__ bias, float* __restrict__ out) {
    size_t t = (size_t)blockIdx.x * 256 + threadIdx.x;
    if (t >= (size_t)B_ * O_ * M_) return;
    int m = (int)(t % M_);
    int o = (int)((t / M_) % O_);
    int b = (int)(t / ((size_t)M_ * O_));
    const float* xb = x + (size_t)b * N_ * D_;
    const float* c  = xs + ((size_t)b * M_ + m) * D_;
    const int*   id = idx + ((size_t)b * M_ + m) * K_;
    const float* w1 = W + o * 128;
    const float* w2 = w1 + 64;
    float best = -INFINITY;
    for (int k = 0; k < K_; ++k) {
        const float* g = xb + (size_t)id[k] * D_;
        float s = bias[o];
        for (int d = 0; d < D_; ++d)
            s += (g[d] - c[d]) * w1[d] + c[d] * w2[d];
        best = fmaxf(best, s);
    }
    out[t] = best > 0.0f ? best : 0.0f;
}

extern "C" void kernel_launch(void* const* d_in, const int* in_sizes, int n_in,
                              void* d_out, int out_size, void* d_ws, size_t ws_size,
                              hipStream_t stream) {
    const float* x    = (const float*)d_in[0];
    const float* xs   = (const float*)d_in[1];
    const int*   idx  = (const int*)d_in[2];
    const float* W    = (const float*)d_in[3];
    const float* bias = (const float*)d_in[4];
    float* out = (float*)d_out;

    const size_t needG = (size_t)B_ * N_ * 64 * sizeof(__half);  // 16.78 MB
    const size_t needC = (size_t)B_ * M_ * 64 * sizeof(__half);  //  4.19 MB

    if (ws_size < needG + needC) {
        size_t total = (size_t)B_ * O_ * M_;
        naive_all<<<(int)((total + 255) / 256), 256, 0, stream>>>(x, xs, idx, W, bias, out);
        return;
    }

    __half* G = (__half*)d_ws;
    __half* C = (__half*)((char*)d_ws + needG);

    // PROBE ROUND: A x6, B x5 internal repeats (rep_off = 0 -> identical work
    // each rep, deterministic output). Next round reverts to reps=1.
    gemm_gc<<<1280, 256, 0, stream>>>(x, xs, W, bias, G, C, 6, 0L);
    gather_max<<<(B_ * M_) / 32, 512, 0, stream>>>(idx, G, C, out, 5, 0L);
}

// Round 8
// 33.400 us; speedup vs baseline: 4.7430x; 4.7430x over previous
//
#include <hip/hip_runtime.h>
#include <hip/hip_fp16.h>
#include <math.h>

#define B_ 4
#define N_ 32768
#define M_ 8192
#define K_ 16
#define D_ 64
#define O_ 64

typedef __attribute__((ext_vector_type(8))) short bf16x8;
typedef __attribute__((ext_vector_type(4))) float f32x4;

// float -> bf16 bits, round-to-nearest-even (inputs are finite normals)
static __device__ __forceinline__ short f2bf(float f) {
    unsigned u = __float_as_uint(f);
    u += 0x7fffu + ((u >> 16) & 1u);
    return (short)(u >> 16);
}

static __device__ __forceinline__ __half2 i2h2(int v) {
    __half2 r;
    *reinterpret_cast<int*>(&r) = v;
    return r;
}

// ---------------------------------------------------------------------------
// Kernel A (MFMA, no LDS) — at HBM roofline (R6 probe: ~9.3us vs 8.9 floor).
//   G[b*N+n][64] fp16 = x-row . W1           (permuted col order: pos p holds
//   C[b*M+m][64] fp16 = xs-row . (W2-W1) + b  o = (p&3)*16 + (p>>2))
// Wave = 32 rows (2 MFMA 16-row tiles), 5120 waves (5/SIMD).
// ---------------------------------------------------------------------------
__global__ __launch_bounds__(256)
void gemm_gc(const float* __restrict__ x, const float* __restrict__ xs,
             const float* __restrict__ W, const float* __restrict__ bias,
             __half* __restrict__ G, __half* __restrict__ C) {
    const int tid = threadIdx.x;
    const int l   = tid & 63;
    const int lr  = l & 15;          // A-row / B-col within tile
    const int kg  = l >> 4;          // k-group (8 consecutive k each)
    const int job = blockIdx.x * 4 + (tid >> 6);     // 0..5119, 32 rows each
    const bool cmode = job >= (B_ * N_) / 32;        // jobs 4096..5119

    // ---- B fragments: bf[s][t] covers k = s*32 + kg*8 + 0..7, o = t*16 + lr
    bf16x8 bf[2][4];
    float  binit[4] = {0.f, 0.f, 0.f, 0.f};
    #pragma unroll
    for (int t = 0; t < 4; ++t) {
        #pragma unroll
        for (int s = 0; s < 2; ++s) {
            const float* wp = W + (size_t)(t * 16 + lr) * 128 + s * 32 + kg * 8;
            float4 f0 = *(const float4*)wp;
            float4 f1 = *(const float4*)(wp + 4);
            if (cmode) {
                float4 g0 = *(const float4*)(wp + 64);
                float4 g1 = *(const float4*)(wp + 68);
                f0.x = g0.x - f0.x; f0.y = g0.y - f0.y;
                f0.z = g0.z - f0.z; f0.w = g0.w - f0.w;
                f1.x = g1.x - f1.x; f1.y = g1.y - f1.y;
                f1.z = g1.z - f1.z; f1.w = g1.w - f1.w;
            }
            bf16x8 v;
            v[0] = f2bf(f0.x); v[1] = f2bf(f0.y); v[2] = f2bf(f0.z); v[3] = f2bf(f0.w);
            v[4] = f2bf(f1.x); v[5] = f2bf(f1.y); v[6] = f2bf(f1.z); v[7] = f2bf(f1.w);
            bf[s][t] = v;
        }
    }
    if (cmode) {
        #pragma unroll
        for (int t = 0; t < 4; ++t) binit[t] = bias[t * 16 + lr];
    }

    const long rows0 = (cmode ? (long)(job - (B_ * N_) / 32) : (long)job) * 32;
    const float* src = cmode ? xs : x;
    __half* dst = cmode ? C : G;

    #pragma unroll
    for (int i = 0; i < 2; ++i) {
        const long r0 = rows0 + i * 16;

        bf16x8 af[2];
        #pragma unroll
        for (int s = 0; s < 2; ++s) {
            const float* xp = src + (size_t)(r0 + lr) * 64 + s * 32 + kg * 8;
            float4 f0 = *(const float4*)xp;
            float4 f1 = *(const float4*)(xp + 4);
            bf16x8 v;
            v[0] = f2bf(f0.x); v[1] = f2bf(f0.y); v[2] = f2bf(f0.z); v[3] = f2bf(f0.w);
            v[4] = f2bf(f1.x); v[5] = f2bf(f1.y); v[6] = f2bf(f1.z); v[7] = f2bf(f1.w);
            af[s] = v;
        }

        f32x4 acc[4];
        #pragma unroll
        for (int t = 0; t < 4; ++t) {
            f32x4 a = {binit[t], binit[t], binit[t], binit[t]};
            a = __builtin_amdgcn_mfma_f32_16x16x32_bf16(af[0], bf[0][t], a, 0, 0, 0);
            a = __builtin_amdgcn_mfma_f32_16x16x32_bf16(af[1], bf[1][t], a, 0, 0, 0);
            acc[t] = a;
        }

        // D: lane holds rows (kg*4 + r), col lr, for 4 o-tiles t.
        // Permuted row storage: element lr*4 + t -> 4 contiguous fp16.
        #pragma unroll
        for (int r = 0; r < 4; ++r) {
            unsigned lo = (unsigned)__half_as_ushort(__float2half(acc[0][r]))
                        | ((unsigned)__half_as_ushort(__float2half(acc[1][r])) << 16);
            unsigned hi = (unsigned)__half_as_ushort(__float2half(acc[2][r]))
                        | ((unsigned)__half_as_ushort(__float2half(acc[3][r])) << 16);
            __half* hp = dst + (size_t)(r0 + kg * 4 + r) * 64 + lr * 4;
            int2 pv; pv.x = (int)lo; pv.y = (int)hi;
            *(int2*)hp = pv;
        }
    }
}

// ---------------------------------------------------------------------------
// Kernel B (R7 redesign, R8 compile fix: unpack+fmaxf instead of __hmax2):
// Wave = 4 m. Lane j = (slot = j>>4 -> which m, q = j&15 -> 8B col chunk).
// Gather instruction k loads G rows idx[m_slot][k] for the 4 slots at once
// (4 x 128B lines, 16 lanes x int2 each): 16 VMEM issues per wave instead
// of 64. Max over k privatized per thread (slot==m, no cross-lane reduce).
// Cols 4q+r hold o = r*16+q (kernel A's permuted order); LDS transpose
// (stride 36 -> 2-way conflicts = free) then coalesced float4 stores.
// Batch-affine XCD swizzle kept from R5.
// ---------------------------------------------------------------------------
__global__ __launch_bounds__(512)
void gather_max(const int* __restrict__ idx, const __half* __restrict__ G,
                const __half* __restrict__ C, float* __restrict__ out) {
    __shared__ int   ldsI[512];        // 32 m x 16 k
    __shared__ float ldsT[64 * 36];
    const int tid = threadIdx.x;
    const int blk = blockIdx.x;          // 0..1023
    const int xcd  = blk & 7;
    const int slot8 = blk >> 3;          // 0..127
    const int bb   = xcd >> 1;           // batch on XCD pair {2c, 2c+1}
    const int m0   = ((((xcd & 1) << 7) + slot8) << 5);   // m-tile * 32

    ldsI[tid] = idx[((size_t)bb * M_ + m0) * 16 + tid];
    __syncthreads();

    const int j    = tid & 63;
    const int wv   = tid >> 6;           // 0..7
    const int slot = j >> 4;             // which m of the wave's 4
    const int q    = j & 15;             // 8B chunk within 128B row
    const int mloc = wv * 4 + slot;      // m within block tile (0..31)

    // this lane's 16 neighbor rows (16-lane broadcast groups in LDS)
    int rr[16];
    #pragma unroll
    for (int k4 = 0; k4 < 4; ++k4) {
        int4 t4 = *(const int4*)&ldsI[mloc * 16 + k4 * 4];
        rr[k4 * 4 + 0] = t4.x; rr[k4 * 4 + 1] = t4.y;
        rr[k4 * 4 + 2] = t4.z; rr[k4 * 4 + 3] = t4.w;
    }

    // gather: 16 x int2 (4 halfs each)
    const int2* gp = (const int2*)(G + (size_t)bb * N_ * 64);
    int2 gv[16];
    #pragma unroll
    for (int k = 0; k < 16; ++k) {
        unsigned off = (unsigned)rr[k] * 16u + (unsigned)q;   // int2 units
        gv[k] = gp[off];
    }

    float m0f = -INFINITY, m1f = -INFINITY, m2f = -INFINITY, m3f = -INFINITY;
    #pragma unroll
    for (int k = 0; k < 16; ++k) {
        float2 a = __half22float2(i2h2(gv[k].x));
        float2 b = __half22float2(i2h2(gv[k].y));
        m0f = fmaxf(m0f, a.x);
        m1f = fmaxf(m1f, a.y);
        m2f = fmaxf(m2f, b.x);
        m3f = fmaxf(m3f, b.y);
    }

    // C row for this m (wave covers 4 consecutive rows = 512B contiguous)
    int2 cc = *(const int2*)(C + ((size_t)bb * M_ + m0 + mloc) * 64 + q * 4);
    float2 c0 = __half22float2(i2h2(cc.x));
    float2 c1 = __half22float2(i2h2(cc.y));

    float v0 = m0f + c0.x, v1 = m1f + c0.y;
    float v2 = m2f + c1.x, v3 = m3f + c1.y;
    // col 4q+r -> o = r*16 + q
    ldsT[(0 * 16 + q) * 36 + mloc] = v0 > 0.f ? v0 : 0.f;
    ldsT[(1 * 16 + q) * 36 + mloc] = v1 > 0.f ? v1 : 0.f;
    ldsT[(2 * 16 + q) * 36 + mloc] = v2 > 0.f ? v2 : 0.f;
    ldsT[(3 * 16 + q) * 36 + mloc] = v3 > 0.f ? v3 : 0.f;
    __syncthreads();

    // out: thread t -> o = t>>3, 4 consecutive m at (t&7)*4
    const int o  = tid >> 3;
    const int ms = (tid & 7) * 4;
    float4 v = make_float4(ldsT[o * 36 + ms + 0], ldsT[o * 36 + ms + 1],
                           ldsT[o * 36 + ms + 2], ldsT[o * 36 + ms + 3]);
    *(float4*)(out + ((size_t)bb * 64 + o) * M_ + m0 + ms) = v;
}

// ---------------------------------------------------------------------------
// Naive exact fallback (only if ws too small).
// ---------------------------------------------------------------------------
__global__ void naive_all(const float* __restrict__ x, const float* __restrict__ xs,
                          const int* __restrict__ idx, const float* __restrict__ W,
                          const float* __restrict__ bias, float* __restrict__ out) {
    size_t t = (size_t)blockIdx.x * 256 + threadIdx.x;
    if (t >= (size_t)B_ * O_ * M_) return;
    int m = (int)(t % M_);
    int o = (int)((t / M_) % O_);
    int b = (int)(t / ((size_t)M_ * O_));
    const float* xb = x + (size_t)b * N_ * D_;
    const float* c  = xs + ((size_t)b * M_ + m) * D_;
    const int*   id = idx + ((size_t)b * M_ + m) * K_;
    const float* w1 = W + o * 128;
    const float* w2 = w1 + 64;
    float best = -INFINITY;
    for (int k = 0; k < K_; ++k) {
        const float* g = xb + (size_t)id[k] * D_;
        float s = bias[o];
        for (int d = 0; d < D_; ++d)
            s += (g[d] - c[d]) * w1[d] + c[d] * w2[d];
        best = fmaxf(best, s);
    }
    out[t] = best > 0.0f ? best : 0.0f;
}

extern "C" void kernel_launch(void* const* d_in, const int* in_sizes, int n_in,
                              void* d_out, int out_size, void* d_ws, size_t ws_size,
                              hipStream_t stream) {
    const float* x    = (const float*)d_in[0];
    const float* xs   = (const float*)d_in[1];
    const int*   idx  = (const int*)d_in[2];
    const float* W    = (const float*)d_in[3];
    const float* bias = (const float*)d_in[4];
    float* out = (float*)d_out;

    const size_t needG = (size_t)B_ * N_ * 64 * sizeof(__half);  // 16.78 MB
    const size_t needC = (size_t)B_ * M_ * 64 * sizeof(__half);  //  4.19 MB

    if (ws_size < needG + needC) {
        size_t total = (size_t)B_ * O_ * M_;
        naive_all<<<(int)((total + 255) / 256), 256, 0, stream>>>(x, xs, idx, W, bias, out);
        return;
    }

    __half* G = (__half*)d_ws;
    __half* C = (__half*)((char*)d_ws + needG);

    // 5120 jobs of 32 rows (4096 G + 1024 C), 4 waves/block
    gemm_gc<<<1280, 256, 0, stream>>>(x, xs, W, bias, G, C);
    // 1024 blocks x 512 threads, 32 m per block
    gather_max<<<(B_ * M_) / 32, 512, 0, stream>>>(idx, G, C, out);
}

// Round 9
// 33.016 us; speedup vs baseline: 4.7982x; 1.0116x over previous
//
#include <hip/hip_runtime.h>
#include <math.h>

#define B_ 4
#define N_ 32768
#define M_ 8192
#define K_ 16
#define D_ 64
#define O_ 64

typedef __attribute__((ext_vector_type(8))) short bf16x8;
typedef __attribute__((ext_vector_type(4))) float f32x4;

// float -> bf16 bits, round-to-nearest-even (inputs are finite normals)
static __device__ __forceinline__ short f2bf(float f) {
    unsigned u = __float_as_uint(f);
    u += 0x7fffu + ((u >> 16) & 1u);
    return (short)(u >> 16);
}

// 8 consecutive floats -> bf16x8 (one MFMA k-chunk)
static __device__ __forceinline__ bf16x8 ld_bf8(const float* p) {
    float4 f0 = *(const float4*)p;
    float4 f1 = *(const float4*)(p + 4);
    bf16x8 v;
    v[0] = f2bf(f0.x); v[1] = f2bf(f0.y); v[2] = f2bf(f0.z); v[3] = f2bf(f0.w);
    v[4] = f2bf(f1.x); v[5] = f2bf(f1.y); v[6] = f2bf(f1.z); v[7] = f2bf(f1.w);
    return v;
}

// ---------------------------------------------------------------------------
// Fused kernel (R9): out[b,o,m] = relu( max_k (x[b,idx[m,k]].W1[o])
//                                       + xs[b,m].(W2-W1)[o] + bias[o] )
// One kernel: no G workspace, no inter-kernel flush/gap, no fp16 rounding.
// Block = 256 thr = 4 waves = 64 consecutive m of one batch; wave = 16 m.
// Per m: gather 16 neighbor rows DIRECTLY as the MFMA A-fragment
// (lane l: row = idx[m][l&15], k-chunk (l>>4)*8 — the layout proven in the
// R3-R8 kernel A), 2 MFMAs vs resident W1 frags -> 16x64 scores; max over
// the 16 rows = 3 in-lane fmaxf + shfl_xor(16,32) across lane-groups.
// Center term: one xs-tile MFMA vs (W2-W1) frags, bias-init accumulator
// (lane's acc rows are m = kg*4+r -> same lane owns vout slot r).
// Epilogue: LDS transpose (stride 65) -> fully-coalesced 256B out stores.
// ---------------------------------------------------------------------------
__global__ __launch_bounds__(256)
void fused_gconv(const float* __restrict__ x, const float* __restrict__ xs,
                 const int* __restrict__ idx, const float* __restrict__ W,
                 const float* __restrict__ bias, float* __restrict__ out) {
    __shared__ int   ldsI[64 * 16];    // block's 64 m x 16 k indices
    __shared__ float ldsT[64 * 65];    // [o][m] transpose, stride 65

    const int tid  = threadIdx.x;
    const int blk  = blockIdx.x;       // 0..511
    const int bb   = blk >> 7;         // batch
    const int mblk = (blk & 127) * 64; // batch-local m base of block

    // stage idx: 4KB, fully coalesced (256 thr x int4)
    *(int4*)&ldsI[tid * 4] =
        *(const int4*)(idx + ((size_t)bb * M_ + mblk) * 16 + tid * 4);

    const int l  = tid & 63;
    const int wv = tid >> 6;           // wave id -> 16-m group
    const int lr = l & 15;             // fragment row / col
    const int kg = l >> 4;             // k-group
    const int mw = wv * 16;            // group base within block

    // resident fragments: W1 and (W2-W1), o-col = t*16+lr, k = s*32+kg*8..
    bf16x8 b1[2][4], bd[2][4];
    float  binit[4];
    #pragma unroll
    for (int t = 0; t < 4; ++t) {
        #pragma unroll
        for (int s = 0; s < 2; ++s) {
            const float* wp = W + (size_t)(t * 16 + lr) * 128 + s * 32 + kg * 8;
            float4 f0 = *(const float4*)wp;
            float4 f1 = *(const float4*)(wp + 4);
            float4 g0 = *(const float4*)(wp + 64);
            float4 g1 = *(const float4*)(wp + 68);
            bf16x8 v1, vd;
            v1[0] = f2bf(f0.x); v1[1] = f2bf(f0.y); v1[2] = f2bf(f0.z); v1[3] = f2bf(f0.w);
            v1[4] = f2bf(f1.x); v1[5] = f2bf(f1.y); v1[6] = f2bf(f1.z); v1[7] = f2bf(f1.w);
            vd[0] = f2bf(g0.x - f0.x); vd[1] = f2bf(g0.y - f0.y);
            vd[2] = f2bf(g0.z - f0.z); vd[3] = f2bf(g0.w - f0.w);
            vd[4] = f2bf(g1.x - f1.x); vd[5] = f2bf(g1.y - f1.y);
            vd[6] = f2bf(g1.z - f1.z); vd[7] = f2bf(g1.w - f1.w);
            b1[s][t] = v1;
            bd[s][t] = vd;
        }
        binit[t] = bias[t * 16 + lr];
    }

    // center term: xs-tile (rows = group's 16 m) vs (W2-W1), bias-init
    const float* xsp = xs + ((size_t)bb * M_ + mblk + mw + lr) * 64 + kg * 8;
    bf16x8 axs0 = ld_bf8(xsp);
    bf16x8 axs1 = ld_bf8(xsp + 32);

    float vout[4][4];                  // [t][r]: o = t*16+lr, m = kg*4+r
    #pragma unroll
    for (int t = 0; t < 4; ++t) {
        f32x4 a = {binit[t], binit[t], binit[t], binit[t]};
        a = __builtin_amdgcn_mfma_f32_16x16x32_bf16(axs0, bd[0][t], a, 0, 0, 0);
        a = __builtin_amdgcn_mfma_f32_16x16x32_bf16(axs1, bd[1][t], a, 0, 0, 0);
        vout[t][0] = a[0]; vout[t][1] = a[1];
        vout[t][2] = a[2]; vout[t][3] = a[3];
    }

    __syncthreads();                   // ldsI ready

    const float* xb = x + (size_t)bb * N_ * 64;

    // per-m: gather A-frag, 8 MFMAs, row-max, owner-lane accumulate.
    // FULL unroll so vout[t][m&3] is statically indexed (no scratch).
    #pragma unroll
    for (int m = 0; m < 16; ++m) {
        const int rr = ldsI[(mw + m) * 16 + lr];       // 16-lane broadcast
        const float* xp = xb + (size_t)(unsigned)rr * 64 + kg * 8;
        bf16x8 a0 = ld_bf8(xp);
        bf16x8 a1 = ld_bf8(xp + 32);
        #pragma unroll
        for (int t = 0; t < 4; ++t) {
            f32x4 a = {0.f, 0.f, 0.f, 0.f};
            a = __builtin_amdgcn_mfma_f32_16x16x32_bf16(a0, b1[0][t], a, 0, 0, 0);
            a = __builtin_amdgcn_mfma_f32_16x16x32_bf16(a1, b1[1][t], a, 0, 0, 0);
            float v = fmaxf(fmaxf(a[0], a[1]), fmaxf(a[2], a[3]));
            v = fmaxf(v, __shfl_xor(v, 16));
            v = fmaxf(v, __shfl_xor(v, 32));           // max over 16 k-rows
            if ((m >> 2) == kg)                        // owner lane-group
                vout[t][m & 3] += v;
        }
    }

    // relu + LDS transpose write: [o = t*16+lr][m = mw + kg*4 + r]
    #pragma unroll
    for (int t = 0; t < 4; ++t)
        #pragma unroll
        for (int r = 0; r < 4; ++r) {
            float v = vout[t][r];
            ldsT[(t * 16 + lr) * 65 + mw + kg * 4 + r] = v > 0.f ? v : 0.f;
        }
    __syncthreads();

    // coalesced stores: thread tid -> o = tid>>2, 16 m at (tid&3)*16
    const int o  = tid >> 2;
    const int ms = (tid & 3) * 16;
    float* op = out + ((size_t)bb * 64 + o) * M_ + mblk + ms;
    #pragma unroll
    for (int j = 0; j < 4; ++j) {
        const float* lp = &ldsT[o * 65 + ms + j * 4];
        *(float4*)(op + j * 4) = make_float4(lp[0], lp[1], lp[2], lp[3]);
    }
}

extern "C" void kernel_launch(void* const* d_in, const int* in_sizes, int n_in,
                              void* d_out, int out_size, void* d_ws, size_t ws_size,
                              hipStream_t stream) {
    const float* x    = (const float*)d_in[0];
    const float* xs   = (const float*)d_in[1];
    const int*   idx  = (const int*)d_in[2];
    const float* W    = (const float*)d_in[3];
    const float* bias = (const float*)d_in[4];
    float* out = (float*)d_out;

    // one fused kernel, no workspace: 512 blocks x 256 thr (wave = 16 m)
    fused_gconv<<<(B_ * M_) / 64, 256, 0, stream>>>(x, xs, idx, W, bias, out);
}